// Round 7
// baseline (198.564 us; speedup 1.0000x reference)
//
#include <hip/hip_runtime.h>

// ModulatedConv2d: B=16, IN=512, OUT=512, STYLE=512, K=3, H=W=32
// out[b,o] = scale[b,o] * conv2d(x[b,i]*s[b,i], W[o,i])   (shared weights!)
// Conv = one implicit GEMM: M=512 out-ch, N=16384 (b,px), K=9x512.
// x staged as zero-padded NHWC bf16 -> no boundary masking.
//
// R2: LDS bank conflicts fully hidden (swizzle fix cost time) -> unswizzled.
// R3: XCD grid swizzle: FETCH 300->28MB (stays).
// R5: BK=64 (8 outstanding global_load_lds/thread) -> intermittent replay
//     divergence (HW race). BANNED. BK=32 / <=4-deep staging is proven.
// R6: 107us conv, OccupancyPercent 21% => grid-limited at 2 blocks/CU.
// R7: 128x64 tiles -> 1024 blocks -> 4 blocks/CU for 2x barrier-group
//     overlap. 3 staging rounds/step (safe depth 3).

#define BATCH   16
#define CIN     512
#define COUT    512
#define IMG     32
#define PAD_IMG 34

static constexpr float AFF_SCALE = 0.044194173824159216f;  // 1/sqrt(512)
static constexpr float W_SCALE   = 0.014731391274719739f;  // 1/sqrt(512*9)

typedef __bf16 bf16x8 __attribute__((ext_vector_type(8)));
typedef float  f32x4  __attribute__((ext_vector_type(4)));

__device__ inline unsigned short f2bf(float f) {
    union { float f; unsigned int u; } v; v.f = f;
    unsigned int u = v.u;
    unsigned int r = (u + 0x7FFFu + ((u >> 16) & 1u)) >> 16;
    return (unsigned short)r;
}

__device__ inline float waveReduceSum(float v) {
    #pragma unroll
    for (int off = 32; off > 0; off >>= 1) v += __shfl_xor(v, off, 64);
    return v;
}

// ---- kernel 1: fused prep ----
// blocks 0..1023:   repack_w  (wsq[o,i], w_t[e][o][i] bf16)
// blocks 1024..3071: compute_s (s[b,i])
__global__ void prep1(const float* __restrict__ cw,
                      const float* __restrict__ style,
                      const float* __restrict__ aw,
                      const float* __restrict__ ab,
                      unsigned short* __restrict__ w_t,
                      float* __restrict__ wsq,
                      float* __restrict__ s_out) {
    const int tid = threadIdx.x;
    if (blockIdx.x < 1024) {
        __shared__ float wl[2304];
        const float* src = cw + (size_t)blockIdx.x * 2304;
        for (int j = tid; j < 2304; j += 256) wl[j] = src[j];
        __syncthreads();
        const int idx = blockIdx.x * 256 + tid;       // o*512 + i
        const int base = tid * 9;
        float acc = 0.f;
        #pragma unroll
        for (int e = 0; e < 9; ++e) {
            float v = wl[base + e];
            acc += v * v;
            w_t[e * (COUT * CIN) + idx] = f2bf(v);
        }
        wsq[idx] = acc;
    } else {
        const int q = blockIdx.x - 1024;              // 0..2047
        const int b = q >> 7;
        const int i = (q & 127) * 4 + (tid >> 6);
        const int lane = tid & 63;
        float sum = 0.f;
        #pragma unroll
        for (int k = 0; k < 512; k += 64)
            sum += style[b * 512 + k + lane] * aw[i * 512 + k + lane];
        sum = waveReduceSum(sum);
        if (lane == 0)
            s_out[b * 512 + i] = sum * AFF_SCALE + ab[i] + 1.0f;
    }
}

// ---- kernel 2: fused xpad + scale ----
// blocks 0..4351:    x_pad[b][hh][ww][c] = bf16(x[b][c][hh-1][ww-1]*s[b][c])
// blocks 4352..6399: scale[b,o] -- 2048 blocks (b=q>>7 spans 0..15), 1 wave/(b,o)
__global__ void prep2(const float* __restrict__ x,
                      const float* __restrict__ s_in,
                      const float* __restrict__ wsq,
                      unsigned short* __restrict__ xpad,
                      float* __restrict__ scl) {
    const int tid = threadIdx.x;
    if (blockIdx.x >= 4352) {
        const int q = blockIdx.x - 4352;              // 0..2047
        const int b = q >> 7;                         // 0..15
        const int o = (q & 127) * 4 + (tid >> 6);     // 0..511
        const int lane = tid & 63;
        float sum = 0.f;
        #pragma unroll
        for (int i = 0; i < 512; i += 64) {
            float sv = s_in[b * 512 + i + lane];
            sum += sv * sv * wsq[o * 512 + i + lane];
        }
        sum = waveReduceSum(sum);
        if (lane == 0)
            scl[b * 512 + o] = W_SCALE * rsqrtf(W_SCALE * W_SCALE * sum + 1e-8f);
        return;
    }
    const int c0   = blockIdx.x & 7;                  // *64 channels
    const int rest = blockIdx.x >> 3;                 // 0..543
    const int hh   = rest % 34;
    const int b    = rest / 34;
    const int c0b  = c0 * 64;
    unsigned short* rowbase = xpad + (((size_t)b * PAD_IMG + hh) * PAD_IMG) * 512;

    if (hh == 0 || hh == PAD_IMG - 1) {
        for (int j = tid; j < 34 * 32; j += 256) {
            int ww = j >> 5, cp = (j & 31) * 2;
            *(unsigned int*)(rowbase + (size_t)ww * 512 + c0b + cp) = 0u;
        }
        return;
    }

    __shared__ float t[64][33];
    const int h = hh - 1;
    {
        const int wx = tid & 31;
        const int cb = (tid >> 5) * 8;
        const float* xb = x + (((size_t)b * 512 + c0b + cb) * IMG + h) * IMG + wx;
        #pragma unroll
        for (int j = 0; j < 8; ++j)
            t[cb + j][wx] = xb[(size_t)j * (IMG * IMG)] * s_in[b * 512 + c0b + cb + j];
    }
    __syncthreads();
    {
        const int p  = tid >> 3;
        const int cc = (tid & 7) * 8;
        unsigned short* dst = rowbase + (size_t)(p + 1) * 512 + c0b + cc;
        uint4 pk;
        pk.x = (unsigned)f2bf(t[cc + 0][p]) | ((unsigned)f2bf(t[cc + 1][p]) << 16);
        pk.y = (unsigned)f2bf(t[cc + 2][p]) | ((unsigned)f2bf(t[cc + 3][p]) << 16);
        pk.z = (unsigned)f2bf(t[cc + 4][p]) | ((unsigned)f2bf(t[cc + 5][p]) << 16);
        pk.w = (unsigned)f2bf(t[cc + 6][p]) | ((unsigned)f2bf(t[cc + 7][p]) << 16);
        *(uint4*)dst = pk;
    }
    if (tid < 64) {
        int ww = (tid >> 5) ? (PAD_IMG - 1) : 0;
        int cp = (tid & 31) * 2;
        *(unsigned int*)(rowbase + (size_t)ww * 512 + c0b + cp) = 0u;
    }
}

// ---- kernel 3: implicit-GEMM conv, 128x64 tile, BK=32, bf16 MFMA ----
// grid 1024 (1-D, XCD-swizzled), block 256 (4 waves; each wave 64x32 out).
// 4 blocks/CU (grid/256) for barrier-group overlap; 3 LDS-DMA rounds/step.
__global__ __launch_bounds__(256, 4) void conv_mfma(
    const unsigned short* __restrict__ wt,    // [9][512][512] bf16
    const unsigned short* __restrict__ xpad,  // [16][34][34][512] bf16
    const float* __restrict__ scl,            // [16][512]
    float* __restrict__ out)                  // [16][512][32][32]
{
    __shared__ unsigned short Alds[128 * 32];   // 8 KB
    __shared__ unsigned short Blds[64 * 32];    // 4 KB
    __shared__ float sclds[128];

    const int tid = threadIdx.x;
    // XCD swizzle: id&7 -> XCD. Per XCD: 32 (b,strip) x 4 m-blocks;
    // sb range covers 2 batches' full images -> L2-local B + shared A.
    const int id    = blockIdx.x;
    const int xcd   = id & 7;
    const int local = id >> 3;                    // 0..127
    const int sb    = xcd * 32 + (local >> 2);    // 0..255 = (b, strip)
    const int m0    = (local & 3) * 128;
    const int b     = sb >> 4;                    // 0..15
    const int h0    = (sb & 15) * 2;              // image rows h0, h0+1

    if (tid < 128) sclds[tid] = scl[b * 512 + m0 + tid];

    const int wid  = tid >> 6;
    const int lane = tid & 63;
    const int wm = wid & 1, wn = wid >> 1;        // wn in 0..1

    const f32x4 vzero = {0.f, 0.f, 0.f, 0.f};
    f32x4 acc[4][2];
    #pragma unroll
    for (int i = 0; i < 4; ++i)
        #pragma unroll
        for (int j = 0; j < 2; ++j) acc[i][j] = vzero;

    // staging: rounds 0,1 fill A (512 x 16B chunks), round 2 fills B (256).
    // chunk f: row=f>>2, col=(f&3)*8; LDS dest = f*16B (wave-uniform+lane*16).
    int aOff[2];
    #pragma unroll
    for (int r = 0; r < 2; ++r) {
        int f   = r * 256 + tid;
        aOff[r] = (f >> 2) * 512 + (f & 3) * 8;
    }
    const int brow_f = tid >> 2;                  // 0..63
    const int bOff   = ((brow_f >> 5) * PAD_IMG + (brow_f & 31)) * 512 + (tid & 3) * 8;
    const int ldsA0  = (wid * 64) * 8;            // + lane*8 shorts implied by HW
    const int ldsA1  = (256 + wid * 64) * 8;
    const int ldsB0  = (wid * 64) * 8;

    const int rl   = lane & 15;
    const int kch  = lane >> 4;
    const int arow = (wm * 64 + rl) * 32 + kch * 8;
    const int brow = (wn * 32 + rl) * 32 + kch * 8;

    for (int e = 0; e < 9; ++e) {
        const int kh = e / 3, kw = e % 3;
        const unsigned short* Abase = wt + (size_t)e * (COUT * CIN) + (size_t)m0 * 512;
        const unsigned short* Bbase =
            xpad + (((size_t)b * PAD_IMG + h0 + kh) * PAD_IMG + kw) * 512;
        for (int kc = 0; kc < 512; kc += 32) {
            __syncthreads();
            __builtin_amdgcn_global_load_lds(
                (const __attribute__((address_space(1))) void*)(Abase + aOff[0] + kc),
                (__attribute__((address_space(3))) void*)(&Alds[ldsA0]), 16, 0, 0);
            __builtin_amdgcn_global_load_lds(
                (const __attribute__((address_space(1))) void*)(Abase + aOff[1] + kc),
                (__attribute__((address_space(3))) void*)(&Alds[ldsA1]), 16, 0, 0);
            __builtin_amdgcn_global_load_lds(
                (const __attribute__((address_space(1))) void*)(Bbase + bOff + kc),
                (__attribute__((address_space(3))) void*)(&Blds[ldsB0]), 16, 0, 0);
            __syncthreads();

            bf16x8 af[4], bfr[2];
            #pragma unroll
            for (int mi = 0; mi < 4; ++mi)
                af[mi] = *(const bf16x8*)(&Alds[arow + mi * 16 * 32]);
            #pragma unroll
            for (int ni = 0; ni < 2; ++ni)
                bfr[ni] = *(const bf16x8*)(&Blds[brow + ni * 16 * 32]);
            #pragma unroll
            for (int mi = 0; mi < 4; ++mi)
                #pragma unroll
                for (int ni = 0; ni < 2; ++ni)
                    acc[mi][ni] = __builtin_amdgcn_mfma_f32_16x16x32_bf16(
                        af[mi], bfr[ni], acc[mi][ni], 0, 0, 0);
        }
    }

    // epilogue: C[m][n] layout col=lane&15, row=(lane>>4)*4+reg  [m89-verified]
    const int colp = lane & 15;
    const int rowq = (lane >> 4) * 4;
    const int p0 = h0 * 32;
    #pragma unroll
    for (int mi = 0; mi < 4; ++mi) {
        #pragma unroll
        for (int ni = 0; ni < 2; ++ni) {
            const int p = p0 + wn * 32 + ni * 16 + colp;
            #pragma unroll
            for (int r2 = 0; r2 < 4; ++r2) {
                const int ol = wm * 64 + mi * 16 + rowq + r2;
                out[(((size_t)b * 512 + m0 + ol) << 10) + p] =
                    acc[mi][ni][r2] * sclds[ol];
            }
        }
    }
}

extern "C" void kernel_launch(void* const* d_in, const int* in_sizes, int n_in,
                              void* d_out, int out_size, void* d_ws, size_t ws_size,
                              hipStream_t stream) {
    const float* x     = (const float*)d_in[0];  // [16,512,32,32]
    const float* style = (const float*)d_in[1];  // [16,512]
    const float* aw    = (const float*)d_in[2];  // [512,512]
    const float* ab    = (const float*)d_in[3];  // [512]
    const float* cw    = (const float*)d_in[4];  // [512,512,3,3]
    float* out = (float*)d_out;

    char* ws = (char*)d_ws;
    float* s_buf          = (float*)(ws);                      //  32 KB
    float* scl            = (float*)(ws + 32768);              //  32 KB
    float* wsq            = (float*)(ws + 65536);              //   1 MB
    unsigned short* w_t   = (unsigned short*)(ws + 1114112);   // 4.5 MB bf16
    unsigned short* x_pad = (unsigned short*)(ws + 5832704);   // 18.9 MB bf16
    // total ws need: 24,772,608 B

    prep1<<<dim3(3072), 256, 0, stream>>>(cw, style, aw, ab, w_t, wsq, s_buf);
    prep2<<<dim3(6400), 256, 0, stream>>>(x, s_buf, wsq, x_pad, scl);
    conv_mfma<<<dim3(1024), 256, 0, stream>>>(w_t, x_pad, scl, out);
}

// Round 8
// 185.797 us; speedup vs baseline: 1.0687x; 1.0687x over previous
//
#include <hip/hip_runtime.h>

// ModulatedConv2d: B=16, IN=512, OUT=512, STYLE=512, K=3, H=W=32
// out[b,o] = scale[b,o] * conv2d(x[b,i]*s[b,i], W[o,i])   (shared weights!)
// Conv = one implicit GEMM: M=512 out-ch, N=16384 (b,px), K=9x512.
// x staged as zero-padded NHWC bf16 -> no boundary masking.
//
// R3: XCD grid swizzle (FETCH 300->28MB). R5: BK=64 LDS-DMA raced -> banned.
// R6: BK=32 global_load_lds 2-barrier loop: 107us, MfmaUtil 31%, latency-bound.
// R7: 4 blocks/CU via 128x64 tiles REGRESSED (118us, MfmaUtil 27%): per-step
//     drain is fixed cost; halving per-step MFMA work raised overhead ratio.
// R8: restructured K-loop: buffer_load->VGPR prefetch + ds_write dbuf LDS,
//     ONE barrier/step, prefetch stays in flight across it (VGPR loads are
//     not drained by __syncthreads, unlike LDS-DMA). XOR-swizzled LDS layout
//     (free now that we control write addrs) kills the 9.4M bank conflicts.

#define BATCH   16
#define CIN     512
#define COUT    512
#define IMG     32
#define PAD_IMG 34

static constexpr float AFF_SCALE = 0.044194173824159216f;  // 1/sqrt(512)
static constexpr float W_SCALE   = 0.014731391274719739f;  // 1/sqrt(512*9)

typedef __bf16 bf16x8 __attribute__((ext_vector_type(8)));
typedef float  f32x4  __attribute__((ext_vector_type(4)));

__device__ inline unsigned short f2bf(float f) {
    union { float f; unsigned int u; } v; v.f = f;
    unsigned int u = v.u;
    unsigned int r = (u + 0x7FFFu + ((u >> 16) & 1u)) >> 16;
    return (unsigned short)r;
}

__device__ inline float waveReduceSum(float v) {
    #pragma unroll
    for (int off = 32; off > 0; off >>= 1) v += __shfl_xor(v, off, 64);
    return v;
}

// ---- kernel 1: fused prep ----
// blocks 0..1023:   repack_w  (wsq[o,i], w_t[e][o][i] bf16)
// blocks 1024..3071: compute_s (s[b,i])
__global__ void prep1(const float* __restrict__ cw,
                      const float* __restrict__ style,
                      const float* __restrict__ aw,
                      const float* __restrict__ ab,
                      unsigned short* __restrict__ w_t,
                      float* __restrict__ wsq,
                      float* __restrict__ s_out) {
    const int tid = threadIdx.x;
    if (blockIdx.x < 1024) {
        __shared__ float wl[2304];
        const float* src = cw + (size_t)blockIdx.x * 2304;
        for (int j = tid; j < 2304; j += 256) wl[j] = src[j];
        __syncthreads();
        const int idx = blockIdx.x * 256 + tid;       // o*512 + i
        const int base = tid * 9;
        float acc = 0.f;
        #pragma unroll
        for (int e = 0; e < 9; ++e) {
            float v = wl[base + e];
            acc += v * v;
            w_t[e * (COUT * CIN) + idx] = f2bf(v);
        }
        wsq[idx] = acc;
    } else {
        const int q = blockIdx.x - 1024;              // 0..2047
        const int b = q >> 7;
        const int i = (q & 127) * 4 + (tid >> 6);
        const int lane = tid & 63;
        float sum = 0.f;
        #pragma unroll
        for (int k = 0; k < 512; k += 64)
            sum += style[b * 512 + k + lane] * aw[i * 512 + k + lane];
        sum = waveReduceSum(sum);
        if (lane == 0)
            s_out[b * 512 + i] = sum * AFF_SCALE + ab[i] + 1.0f;
    }
}

// ---- kernel 2: fused xpad + scale ----
// blocks 0..4351:    x_pad[b][hh][ww][c] = bf16(x[b][c][hh-1][ww-1]*s[b][c])
// blocks 4352..6399: scale[b,o] -- 2048 blocks (b=q>>7 spans 0..15), 1 wave/(b,o)
__global__ void prep2(const float* __restrict__ x,
                      const float* __restrict__ s_in,
                      const float* __restrict__ wsq,
                      unsigned short* __restrict__ xpad,
                      float* __restrict__ scl) {
    const int tid = threadIdx.x;
    if (blockIdx.x >= 4352) {
        const int q = blockIdx.x - 4352;              // 0..2047
        const int b = q >> 7;                         // 0..15
        const int o = (q & 127) * 4 + (tid >> 6);     // 0..511
        const int lane = tid & 63;
        float sum = 0.f;
        #pragma unroll
        for (int i = 0; i < 512; i += 64) {
            float sv = s_in[b * 512 + i + lane];
            sum += sv * sv * wsq[o * 512 + i + lane];
        }
        sum = waveReduceSum(sum);
        if (lane == 0)
            scl[b * 512 + o] = W_SCALE * rsqrtf(W_SCALE * W_SCALE * sum + 1e-8f);
        return;
    }
    const int c0   = blockIdx.x & 7;                  // *64 channels
    const int rest = blockIdx.x >> 3;                 // 0..543
    const int hh   = rest % 34;
    const int b    = rest / 34;
    const int c0b  = c0 * 64;
    unsigned short* rowbase = xpad + (((size_t)b * PAD_IMG + hh) * PAD_IMG) * 512;

    if (hh == 0 || hh == PAD_IMG - 1) {
        for (int j = tid; j < 34 * 32; j += 256) {
            int ww = j >> 5, cp = (j & 31) * 2;
            *(unsigned int*)(rowbase + (size_t)ww * 512 + c0b + cp) = 0u;
        }
        return;
    }

    __shared__ float t[64][33];
    const int h = hh - 1;
    {
        const int wx = tid & 31;
        const int cb = (tid >> 5) * 8;
        const float* xb = x + (((size_t)b * 512 + c0b + cb) * IMG + h) * IMG + wx;
        #pragma unroll
        for (int j = 0; j < 8; ++j)
            t[cb + j][wx] = xb[(size_t)j * (IMG * IMG)] * s_in[b * 512 + c0b + cb + j];
    }
    __syncthreads();
    {
        const int p  = tid >> 3;
        const int cc = (tid & 7) * 8;
        unsigned short* dst = rowbase + (size_t)(p + 1) * 512 + c0b + cc;
        uint4 pk;
        pk.x = (unsigned)f2bf(t[cc + 0][p]) | ((unsigned)f2bf(t[cc + 1][p]) << 16);
        pk.y = (unsigned)f2bf(t[cc + 2][p]) | ((unsigned)f2bf(t[cc + 3][p]) << 16);
        pk.z = (unsigned)f2bf(t[cc + 4][p]) | ((unsigned)f2bf(t[cc + 5][p]) << 16);
        pk.w = (unsigned)f2bf(t[cc + 6][p]) | ((unsigned)f2bf(t[cc + 7][p]) << 16);
        *(uint4*)dst = pk;
    }
    if (tid < 64) {
        int ww = (tid >> 5) ? (PAD_IMG - 1) : 0;
        int cp = (tid & 31) * 2;
        *(unsigned int*)(rowbase + (size_t)ww * 512 + c0b + cp) = 0u;
    }
}

// ---- kernel 3: implicit-GEMM conv, 128x128 tile, BK=32, bf16 MFMA ----
// Register-staged pipeline: buffer_load->VGPR prefetch, ds_write dbuf LDS,
// one barrier per K-step. grid 512 (XCD-swizzled), block 256 (4 waves).
__global__ __launch_bounds__(256, 2) void conv_mfma(
    const unsigned short* __restrict__ wt,    // [9][512][512] bf16
    const unsigned short* __restrict__ xpad,  // [16][34][34][512] bf16
    const float* __restrict__ scl,            // [16][512]
    float* __restrict__ out)                  // [16][512][32][32]
{
    __shared__ __align__(16) unsigned short Alds[2][128 * 32];  // 2 x 8 KB
    __shared__ __align__(16) unsigned short Blds[2][128 * 32];  // 2 x 8 KB
    __shared__ float sclds[128];

    const int tid = threadIdx.x;
    // XCD swizzle: id&7 -> XCD. Each XCD: 16 (h,b)-pairs x 4 m-blocks.
    const int id    = blockIdx.x;
    const int xcd   = id & 7;
    const int local = id >> 3;                   // 0..63
    const int gp    = xcd * 16 + (local >> 2);   // 0..127  (h,b) pair
    const int m0  = (local & 3) * 128;
    const int h0  = (gp & 7) * 4;
    const int b   = gp >> 3;

    if (tid < 128) sclds[tid] = scl[b * 512 + m0 + tid];

    const int wid  = tid >> 6;
    const int lane = tid & 63;
    const int wm = wid & 1, wn = wid >> 1;

    const f32x4 vzero = {0.f, 0.f, 0.f, 0.f};
    f32x4 acc[4][4];
    #pragma unroll
    for (int i = 0; i < 4; ++i)
        #pragma unroll
        for (int j = 0; j < 4; ++j) acc[i][j] = vzero;

    // staging: thread f = r*256+tid owns (row=f>>2, chunk c=f&3) of the
    // 128x32 tile. Global offset: row*stride + c*8. LDS slot XOR-swizzled:
    // position p = c ^ ((row>>1)&3)  -> ds_write & frag ds_read both 2-way
    // (free) on banks.
    int aOff[2], bOff[2], ldsOff[2];
    #pragma unroll
    for (int r = 0; r < 2; ++r) {
        int f   = r * 256 + tid;
        int row = f >> 2;
        int c   = f & 3;
        int p   = c ^ ((row >> 1) & 3);
        aOff[r]   = row * 512 + c * 8;
        bOff[r]   = ((row >> 5) * PAD_IMG + (row & 31)) * 512 + c * 8;
        ldsOff[r] = row * 32 + p * 8;            // shorts
    }

    const size_t bImgBase = (size_t)b * PAD_IMG * PAD_IMG * 512;

    // prefetch loader: step -> 4 x dwordx4 into regs
    uint4 ra0, ra1, rb0, rb1;
    auto loadStep = [&](int step) {
        const int e  = step >> 4;
        const int kc = (step & 15) << 5;
        const int kh = (e * 11) >> 5;            // e/3 for e<9
        const int kw = e - kh * 3;
        const unsigned short* Ab = wt + (size_t)e * (COUT * CIN)
                                      + (size_t)m0 * 512 + kc;
        const unsigned short* Bb = xpad + bImgBase
                                 + (size_t)((h0 + kh) * PAD_IMG + kw) * 512 + kc;
        ra0 = *(const uint4*)(Ab + aOff[0]);
        ra1 = *(const uint4*)(Ab + aOff[1]);
        rb0 = *(const uint4*)(Bb + bOff[0]);
        rb1 = *(const uint4*)(Bb + bOff[1]);
    };

    loadStep(0);

    // fragment read addresses (shorts): row R = wbase+rl, chunk kch at
    // swizzled position kch ^ ((R>>1)&3); wbase%16==0 so (R>>1)&3=(rl>>1)&3.
    const int rl   = lane & 15;
    const int kch  = lane >> 4;
    const int swz  = (kch ^ ((rl >> 1) & 3)) * 8;
    const int arow = (wm * 64 + rl) * 32 + swz;
    const int brow = (wn * 64 + rl) * 32 + swz;

    for (int step = 0; step < 144; ++step) {
        const int buf = step & 1;
        // commit prefetched regs to LDS (vmcnt wait here is for loads issued
        // one full iteration ago -- hidden behind compute(step-1))
        *(uint4*)(&Alds[buf][ldsOff[0]]) = ra0;
        *(uint4*)(&Alds[buf][ldsOff[1]]) = ra1;
        *(uint4*)(&Blds[buf][ldsOff[0]]) = rb0;
        *(uint4*)(&Blds[buf][ldsOff[1]]) = rb1;
        // issue next step's loads; they remain in flight across the barrier
        loadStep(step + 1 < 144 ? step + 1 : 143);
        __syncthreads();

        bf16x8 af[4], bfr[4];
        #pragma unroll
        for (int mi = 0; mi < 4; ++mi)
            af[mi] = *(const bf16x8*)(&Alds[buf][arow + mi * 16 * 32]);
        #pragma unroll
        for (int ni = 0; ni < 4; ++ni)
            bfr[ni] = *(const bf16x8*)(&Blds[buf][brow + ni * 16 * 32]);
        #pragma unroll
        for (int mi = 0; mi < 4; ++mi)
            #pragma unroll
            for (int ni = 0; ni < 4; ++ni)
                acc[mi][ni] = __builtin_amdgcn_mfma_f32_16x16x32_bf16(
                    af[mi], bfr[ni], acc[mi][ni], 0, 0, 0);
        // no second barrier needed: next iter's ds_write targets buf^1,
        // whose last readers (step-1) provably finished before barrier(step).
    }

    // epilogue: C[m][n] layout col=lane&15, row=(lane>>4)*4+reg  [m89-verified]
    const int colp = lane & 15;
    const int rowq = (lane >> 4) * 4;
    const int p0 = h0 * 32;
    #pragma unroll
    for (int mi = 0; mi < 4; ++mi) {
        #pragma unroll
        for (int ni = 0; ni < 4; ++ni) {
            const int p = p0 + wn * 64 + ni * 16 + colp;
            #pragma unroll
            for (int r2 = 0; r2 < 4; ++r2) {
                const int ol = wm * 64 + mi * 16 + rowq + r2;
                out[(((size_t)b * 512 + m0 + ol) << 10) + p] =
                    acc[mi][ni][r2] * sclds[ol];
            }
        }
    }
}

extern "C" void kernel_launch(void* const* d_in, const int* in_sizes, int n_in,
                              void* d_out, int out_size, void* d_ws, size_t ws_size,
                              hipStream_t stream) {
    const float* x     = (const float*)d_in[0];  // [16,512,32,32]
    const float* style = (const float*)d_in[1];  // [16,512]
    const float* aw    = (const float*)d_in[2];  // [512,512]
    const float* ab    = (const float*)d_in[3];  // [512]
    const float* cw    = (const float*)d_in[4];  // [512,512,3,3]
    float* out = (float*)d_out;

    char* ws = (char*)d_ws;
    float* s_buf          = (float*)(ws);                      //  32 KB
    float* scl            = (float*)(ws + 32768);              //  32 KB
    float* wsq            = (float*)(ws + 65536);              //   1 MB
    unsigned short* w_t   = (unsigned short*)(ws + 1114112);   // 4.5 MB bf16
    unsigned short* x_pad = (unsigned short*)(ws + 5832704);   // 18.9 MB bf16
    // total ws need: 24,772,608 B

    prep1<<<dim3(3072), 256, 0, stream>>>(cw, style, aw, ab, w_t, wsq, s_buf);
    prep2<<<dim3(6400), 256, 0, stream>>>(x, s_buf, wsq, x_pad, scl);
    conv_mfma<<<dim3(512), 256, 0, stream>>>(w_t, x_pad, scl, out);
}